// Round 1
// baseline (1031.357 us; speedup 1.0000x reference)
//
#include <hip/hip_runtime.h>

#define N_NODES 50000
#define E_EDGES 262144
#define HID 256

typedef __attribute__((ext_vector_type(8))) short bf16x8;
typedef __attribute__((ext_vector_type(4))) float f32x4;

union V16 { uint4 u; bf16x8 h; };

__device__ __forceinline__ unsigned rne_pack(float a, float b) {
  unsigned ua = __float_as_uint(a); ua += 0x7fffu + ((ua >> 16) & 1u);
  unsigned ub = __float_as_uint(b); ub += 0x7fffu + ((ub >> 16) & 1u);
  return (ua >> 16) | (ub & 0xffff0000u);
}
__device__ __forceinline__ unsigned trunc_pack(float a, float b) {
  return (__float_as_uint(a) >> 16) | (__float_as_uint(b) & 0xffff0000u);
}
__device__ __forceinline__ float bflo(unsigned u) { return __uint_as_float(u << 16); }
__device__ __forceinline__ float bfhi(unsigned u) { return __uint_as_float(u & 0xffff0000u); }

// ---- prep: node_repr fp32 -> bf16 (RNE), 8 elems/thread ----
__global__ void cvt_node_kernel(const float* __restrict__ x, unsigned short* __restrict__ y) {
  int i = (blockIdx.x * 256 + threadIdx.x) * 8;
  float4 f0 = *(const float4*)(x + i);
  float4 f1 = *(const float4*)(x + i + 4);
  uint4 o;
  o.x = rne_pack(f0.x, f0.y);
  o.y = rne_pack(f0.z, f0.w);
  o.z = rne_pack(f1.x, f1.y);
  o.w = rne_pack(f1.z, f1.w);
  *(uint4*)(y + i) = o;
}

// ---- prep: W1 (1024x512, row-major in->out) -> W1T bf16 (512 rows x 1024 cols) ----
__global__ void prep_w1t_kernel(const float* __restrict__ w1, unsigned short* __restrict__ w1t) {
  int t = blockIdx.x * 256 + threadIdx.x;  // 65536 threads
  int n = t >> 7;               // 0..511
  int kc = (t & 127) << 3;      // 0..1016 step 8
  float f[8];
#pragma unroll
  for (int i = 0; i < 8; ++i) f[i] = w1[(size_t)(kc + i) * 512 + n];
  uint4 o;
  o.x = rne_pack(f[0], f[1]);
  o.y = rne_pack(f[2], f[3]);
  o.z = rne_pack(f[4], f[5]);
  o.w = rne_pack(f[6], f[7]);
  *(uint4*)(w1t + (size_t)n * 1024 + kc) = o;
}

// ---- prep: out[e][c] = b2[c] ----
__global__ void init_out_kernel(float* __restrict__ out, const float* __restrict__ b2) {
  int i = blockIdx.x * 256 + threadIdx.x;
  float2 v; v.x = b2[0]; v.y = b2[1];
  *(float2*)(out + (size_t)i * 2) = v;
}

// ---- main fused kernel: gather + section build + GEMM1 + bias/ReLU + GEMM2 + atomic out ----
__global__ __launch_bounds__(256) void edge_mlp_kernel(
    const unsigned short* __restrict__ nodeb,  // [50000][256] bf16
    const unsigned short* __restrict__ w1t,    // [512][1024]  bf16 (W1 transposed)
    const int* __restrict__ src,
    const int* __restrict__ dst,
    const float* __restrict__ b1,
    const float* __restrict__ w2,   // [512][2] fp32
    float* __restrict__ out) {      // [E][2]   fp32, pre-initialized with b2
  const int tid = threadIdx.x;
  const int wid = tid >> 6;
  const int lane = tid & 63;
  const int quad = lane >> 4;
  const int l16 = lane & 15;
  const int bx = blockIdx.x;
  // swizzle: 4 sibling n-blocks of one m-tile land on the same XCD (bx % 8)
  const int m_idx = ((bx >> 5) << 3) + (bx & 7);   // 0..2047
  const int n_idx = (bx >> 3) & 3;                 // 0..3
  const int wave_m = wid >> 1;                     // 0..1
  const int wave_n = wid & 1;                      // 0..1
  const int row0 = m_idx * 128 + wave_m * 64;
  const int n0 = n_idx * 128 + wave_n * 64;

  const char* nodeB = (const char*)nodeb;
  const char* w1tB = (const char*)w1t;

  const char* api[4];
  const char* apj[4];
#pragma unroll
  for (int mt = 0; mt < 4; ++mt) {
    int e = row0 + mt * 16 + l16;
    api[mt] = nodeB + ((size_t)src[e] << 9) + (quad << 4);
    apj[mt] = nodeB + ((size_t)dst[e] << 9) + (quad << 4);
  }
  const char* bp[4];
#pragma unroll
  for (int nt = 0; nt < 4; ++nt)
    bp[nt] = w1tB + ((size_t)(n0 + nt * 16 + l16) << 11) + (quad << 4);

  f32x4 acc[4][4];
#pragma unroll
  for (int mt = 0; mt < 4; ++mt)
#pragma unroll
    for (int nt = 0; nt < 4; ++nt)
      acc[mt][nt] = (f32x4){0.f, 0.f, 0.f, 0.f};

#pragma unroll 1
  for (int c0 = 0; c0 < 256; c0 += 64) {
#pragma unroll
    for (int ks = 0; ks < 2; ++ks) {
      const int ao = (c0 + ks * 32) * 2;  // byte offset within node row
      V16 hi[4], hj[4];
#pragma unroll
      for (int mt = 0; mt < 4; ++mt) {
        hi[mt].u = *(const uint4*)(api[mt] + ao);
        hj[mt].u = *(const uint4*)(apj[mt] + ao);
      }
      // build |hi-hj| (a2) and hi*hj (a3) fragments in registers
      V16 a2[4], a3[4];
#pragma unroll
      for (int mt = 0; mt < 4; ++mt) {
        unsigned d[4], p[4];
        const unsigned hw[4] = {hi[mt].u.x, hi[mt].u.y, hi[mt].u.z, hi[mt].u.w};
        const unsigned jw[4] = {hj[mt].u.x, hj[mt].u.y, hj[mt].u.z, hj[mt].u.w};
#pragma unroll
        for (int w = 0; w < 4; ++w) {
          float i0 = bflo(hw[w]), i1 = bfhi(hw[w]);
          float j0 = bflo(jw[w]), j1 = bfhi(jw[w]);
          d[w] = trunc_pack(fabsf(i0 - j0), fabsf(i1 - j1));
          p[w] = trunc_pack(i0 * j0, i1 * j1);
        }
        a2[mt].u = make_uint4(d[0], d[1], d[2], d[3]);
        a3[mt].u = make_uint4(p[0], p[1], p[2], p[3]);
      }
#pragma unroll
      for (int s = 0; s < 4; ++s) {
        const int bo = s * 512 + ao;  // W1T column byte offset: section s starts at k = s*256
        bf16x8 bfr[4];
#pragma unroll
        for (int nt = 0; nt < 4; ++nt) {
          V16 t;
          t.u = *(const uint4*)(bp[nt] + bo);
          bfr[nt] = t.h;
        }
#pragma unroll
        for (int mt = 0; mt < 4; ++mt) {
          bf16x8 af = (s == 0) ? hi[mt].h : (s == 1) ? hj[mt].h : (s == 2) ? a2[mt].h : a3[mt].h;
#pragma unroll
          for (int nt = 0; nt < 4; ++nt) {
            acc[mt][nt] = __builtin_amdgcn_mfma_f32_16x16x32_bf16(af, bfr[nt], acc[mt][nt], 0, 0, 0);
          }
        }
      }
    }
  }

  // epilogue: bias + ReLU + (h @ W2) partial, reduce over 16-lane col group, atomic add
#pragma unroll
  for (int mt = 0; mt < 4; ++mt) {
    float pc0[4] = {0.f, 0.f, 0.f, 0.f};
    float pc1[4] = {0.f, 0.f, 0.f, 0.f};
#pragma unroll
    for (int nt = 0; nt < 4; ++nt) {
      int gc = n0 + nt * 16 + l16;
      float b1v = b1[gc];
      float w20 = w2[gc * 2 + 0];
      float w21 = w2[gc * 2 + 1];
#pragma unroll
      for (int r = 0; r < 4; ++r) {
        float v = acc[mt][nt][r] + b1v;
        v = fmaxf(v, 0.f);
        pc0[r] = fmaf(v, w20, pc0[r]);
        pc1[r] = fmaf(v, w21, pc1[r]);
      }
    }
#pragma unroll
    for (int r = 0; r < 4; ++r) {
      float s0 = pc0[r], s1 = pc1[r];
#pragma unroll
      for (int off = 1; off < 16; off <<= 1) {
        s0 += __shfl_xor(s0, off);
        s1 += __shfl_xor(s1, off);
      }
      int e = row0 + mt * 16 + quad * 4 + r;  // C/D layout: row = quad*4 + r
      if (l16 == 0) unsafeAtomicAdd(&out[(size_t)e * 2 + 0], s0);
      if (l16 == 1) unsafeAtomicAdd(&out[(size_t)e * 2 + 1], s1);
    }
  }
}

extern "C" void kernel_launch(void* const* d_in, const int* in_sizes, int n_in,
                              void* d_out, int out_size, void* d_ws, size_t ws_size,
                              hipStream_t stream) {
  const float* node = (const float*)d_in[0];
  const int* src = (const int*)d_in[1];
  const int* dst = (const int*)d_in[2];
  const float* W1 = (const float*)d_in[3];
  const float* b1 = (const float*)d_in[4];
  const float* W2 = (const float*)d_in[5];
  const float* b2 = (const float*)d_in[6];
  float* out = (float*)d_out;

  unsigned short* nodeb = (unsigned short*)d_ws;                       // 25,600,000 B
  unsigned short* w1t = (unsigned short*)((char*)d_ws + 25600000);     // 1,048,576 B

  // node_repr: 50000*256 = 12,800,000 elems / 8 per thread = 1,600,000 threads
  cvt_node_kernel<<<6250, 256, 0, stream>>>(node, nodeb);
  // W1T: 512*128 = 65536 threads
  prep_w1t_kernel<<<256, 256, 0, stream>>>(W1, w1t);
  // out init: 262144 threads
  init_out_kernel<<<1024, 256, 0, stream>>>(out, b2);
  // main: 2048 m-blocks x 4 n-blocks
  edge_mlp_kernel<<<8192, 256, 0, stream>>>(nodeb, w1t, src, dst, b1, W2, out);
}